// Round 1
// baseline (118.559 us; speedup 1.0000x reference)
//
#include <hip/hip_runtime.h>
#include <hip/hip_bf16.h>
#include <stdint.h>

#define KP    416        // padded rank (396->416) and padded wemb (400->416)
#define RANKD 396
#define WEMB  400
#define TEMB  20
#define TAGS  25
#define BATCH 16
#define LSEQ  128
#define MROWS 126        // L-2
#define NM    2016       // 16*126
#define NMP   2048
#define ABC   15625
#define ABCP  15744      // 123*128
#define SCALE 0.050251890762960605f   // 1/sqrt(396)

typedef __attribute__((ext_vector_type(8))) short short8;
typedef __attribute__((ext_vector_type(4))) float f32x4;

// workspace layout (bytes)
#define OFF_T01  0                         // 2048*416*2      = 1,703,936
#define OFF_T02  1703936                   // 15744*416*2     = 13,099,008
#define OFF_WORD 14802944                  // 16*128*416*2    = 1,703,936
#define OFF_WT   16506880                  // 3*416*416*2     = 1,038,336
#define OFF_G    17545216                  // 3*25*416*4      = 124,800
// total ~17.7 MB

__device__ __forceinline__ uint16_t f2bf(float f) {
    union { float f; uint32_t u; } v; v.f = f;
    uint32_t u = v.u;
    return (uint16_t)((u + 0x7FFFu + ((u >> 16) & 1u)) >> 16);  // RNE
}

// ---- stage 1: word_emb f32 [16][128][400] -> bf16 [16][128][416] (zero-pad e)
__global__ void k_convert_word(const float* __restrict__ w, uint16_t* __restrict__ out) {
    int idx = blockIdx.x * 256 + threadIdx.x;
    if (idx >= BATCH * LSEQ * KP) return;
    int e = idx % KP, row = idx / KP;
    float v = (e < WEMB) ? w[row * WEMB + e] : 0.f;
    out[idx] = f2bf(v);
}

// ---- stage 2: W_i [400][396] f32 -> Wt_i [416][416] bf16 transposed, zero-padded
__global__ void k_build_wt(const float* __restrict__ W1, const float* __restrict__ W2,
                           const float* __restrict__ W3, uint16_t* __restrict__ out) {
    int idx = blockIdx.x * 256 + threadIdx.x;
    if (idx >= 3 * KP * KP) return;
    int j = idx / (KP * KP);
    int rem = idx % (KP * KP);
    int k = rem / KP, e = rem % KP;
    const float* W = (j == 0) ? W1 : (j == 1) ? W2 : W3;
    float v = (k < RANKD && e < WEMB) ? W[e * RANKD + k] : 0.f;
    out[idx] = f2bf(v);
}

// ---- stage 3: g4/g5/g6 fp32 [3][25][416], zero-padded k
__global__ void k_build_g(const float* __restrict__ tag, const float* __restrict__ T1,
                          const float* __restrict__ T2, const float* __restrict__ T3,
                          float* __restrict__ g) {
    int idx = blockIdx.x * 256 + threadIdx.x;
    if (idx >= 3 * TAGS * KP) return;
    int j = idx / (TAGS * KP);
    int rem = idx % (TAGS * KP);
    int a = rem / KP, k = rem % KP;
    const float* T = (j == 0) ? T1 : (j == 1) ? T2 : T3;
    float s = 0.f;
    if (k < RANKD) {
        for (int e = 0; e < TEMB; ++e) s += tag[a * TEMB + e] * T[e * RANKD + k];
    }
    g[idx] = s;
}

// ---- stage 4: temp01 bf16 [2048][416] = (g1*g2*g3)/sqrt(396), via MFMA
__global__ __launch_bounds__(256) void k_build_t01(const uint16_t* __restrict__ word,
                                                   const uint16_t* __restrict__ wt,
                                                   uint16_t* __restrict__ t01) {
    int wid = threadIdx.x >> 6, lane = threadIdx.x & 63;
    int nmtile = blockIdx.x;
    int ktile = blockIdx.y * 4 + wid;
    if (ktile >= KP / 16) return;
    int col_l = lane & 15, kblk = lane >> 4;
    int colk = ktile * 16 + col_l;
    f32x4 acc1 = {0.f, 0.f, 0.f, 0.f}, acc2 = acc1, acc3 = acc1;
    if (nmtile < NM / 16) {
        int nm_a = nmtile * 16 + col_l;          // A-frag row (per-lane)
        int n = nm_a / MROWS, m = nm_a % MROWS;
        const uint16_t* arow = word + (size_t)(n * LSEQ + m) * KP;
        const uint16_t* b1 = wt + (size_t)colk * KP;
        const uint16_t* b2 = wt + (size_t)KP * KP + (size_t)colk * KP;
        const uint16_t* b3 = wt + (size_t)2 * KP * KP + (size_t)colk * KP;
        for (int e0 = 0; e0 < KP; e0 += 32) {
            int eo = e0 + kblk * 8;
            short8 a0 = *(const short8*)(arow + eo);
            short8 a1 = *(const short8*)(arow + KP + eo);
            short8 a2 = *(const short8*)(arow + 2 * KP + eo);
            short8 v1 = *(const short8*)(b1 + eo);
            short8 v2 = *(const short8*)(b2 + eo);
            short8 v3 = *(const short8*)(b3 + eo);
            acc1 = __builtin_amdgcn_mfma_f32_16x16x32_bf16(a0, v1, acc1, 0, 0, 0);
            acc2 = __builtin_amdgcn_mfma_f32_16x16x32_bf16(a1, v2, acc2, 0, 0, 0);
            acc3 = __builtin_amdgcn_mfma_f32_16x16x32_bf16(a2, v3, acc3, 0, 0, 0);
        }
    }
    for (int r = 0; r < 4; ++r) {
        int row = nmtile * 16 + kblk * 4 + r;    // D row
        float v = acc1[r] * acc2[r] * acc3[r] * SCALE;
        t01[(size_t)row * KP + colk] = f2bf(v);
    }
}

// ---- stage 5: temp02 bf16 [15744][416] = g4[a]*g5[b]*g6[c], zero-pad rows
__global__ void k_build_t02(const float* __restrict__ g, uint16_t* __restrict__ t02) {
    int idx = blockIdx.x * 256 + threadIdx.x;
    if (idx >= ABCP * (KP / 8)) return;
    int abc = idx / (KP / 8), kc = idx % (KP / 8);
    int k0 = kc * 8;
    short8 o;
    if (abc < ABC) {
        int a = abc / 625, rem = abc % 625, b = rem / 25, c = rem % 25;
        const float* ga = g + (size_t)a * KP + k0;
        const float* gb = g + (size_t)TAGS * KP + (size_t)b * KP + k0;
        const float* gc = g + (size_t)2 * TAGS * KP + (size_t)c * KP + k0;
        for (int t = 0; t < 8; ++t)
            o[t] = (short)f2bf(ga[t] * gb[t] * gc[t]);
    } else {
        for (int t = 0; t < 8; ++t) o[t] = 0;
    }
    *(short8*)(t02 + (size_t)abc * KP + k0) = o;
}

// ---- stage 6: score[2016][15625] = t01 @ t02^T  (bf16 MFMA, fp32 out)
// block = 4 waves, 128x128 tile; wave = 64x64 (4x4 mfma tiles)
__global__ __launch_bounds__(256) void k_final(const uint16_t* __restrict__ t01,
                                               const uint16_t* __restrict__ t02,
                                               float* __restrict__ out) {
    int wid = threadIdx.x >> 6, lane = threadIdx.x & 63;
    int col_l = lane & 15, kblk = lane >> 4;
    int row0 = blockIdx.x * 128 + (wid >> 1) * 64;
    int col0 = blockIdx.y * 128 + (wid & 1) * 64;
    f32x4 acc[4][4];
    for (int i = 0; i < 4; ++i)
        for (int j = 0; j < 4; ++j)
            acc[i][j] = (f32x4){0.f, 0.f, 0.f, 0.f};
    const uint16_t* abase = t01 + (size_t)(row0 + col_l) * KP + kblk * 8;
    const uint16_t* bbase = t02 + (size_t)(col0 + col_l) * KP + kblk * 8;
    for (int kk = 0; kk < KP; kk += 32) {
        short8 a[4], b[4];
        for (int i = 0; i < 4; ++i) a[i] = *(const short8*)(abase + (size_t)i * 16 * KP + kk);
        for (int j = 0; j < 4; ++j) b[j] = *(const short8*)(bbase + (size_t)j * 16 * KP + kk);
        for (int i = 0; i < 4; ++i)
            for (int j = 0; j < 4; ++j)
                acc[i][j] = __builtin_amdgcn_mfma_f32_16x16x32_bf16(a[i], b[j], acc[i][j], 0, 0, 0);
    }
    for (int i = 0; i < 4; ++i) {
        int row_b = row0 + i * 16 + kblk * 4;
        for (int j = 0; j < 4; ++j) {
            int col = col0 + j * 16 + col_l;
            if (col >= ABC) continue;
            for (int r = 0; r < 4; ++r) {
                int row = row_b + r;
                if (row < NM) out[(size_t)row * ABC + col] = acc[i][j][r];
            }
        }
    }
}

extern "C" void kernel_launch(void* const* d_in, const int* in_sizes, int n_in,
                              void* d_out, int out_size, void* d_ws, size_t ws_size,
                              hipStream_t stream) {
    const float* word = (const float*)d_in[0];
    const float* tag  = (const float*)d_in[1];
    const float* W1   = (const float*)d_in[2];
    const float* W2   = (const float*)d_in[3];
    const float* W3   = (const float*)d_in[4];
    const float* T1   = (const float*)d_in[5];
    const float* T2   = (const float*)d_in[6];
    const float* T3   = (const float*)d_in[7];
    float* out = (float*)d_out;
    char* ws = (char*)d_ws;

    uint16_t* t01   = (uint16_t*)(ws + OFF_T01);
    uint16_t* t02   = (uint16_t*)(ws + OFF_T02);
    uint16_t* wordb = (uint16_t*)(ws + OFF_WORD);
    uint16_t* wt    = (uint16_t*)(ws + OFF_WT);
    float*    g     = (float*)(ws + OFF_G);

    k_convert_word<<<(BATCH * LSEQ * KP + 255) / 256, 256, 0, stream>>>(word, wordb);
    k_build_wt<<<(3 * KP * KP + 255) / 256, 256, 0, stream>>>(W1, W2, W3, wt);
    k_build_g<<<(3 * TAGS * KP + 255) / 256, 256, 0, stream>>>(tag, T1, T2, T3, g);
    k_build_t01<<<dim3(NMP / 16, 7), 256, 0, stream>>>(wordb, wt, t01);
    k_build_t02<<<(ABCP * (KP / 8) + 255) / 256, 256, 0, stream>>>(g, t02);
    k_final<<<dim3(NMP / 128, ABCP / 128), 256, 0, stream>>>(t01, t02, out);
}

// Round 2
// 87.898 us; speedup vs baseline: 1.3488x; 1.3488x over previous
//
#include <hip/hip_runtime.h>
#include <hip/hip_bf16.h>
#include <stdint.h>

#define KP    416        // padded rank (396->416) and padded wemb (400->416)
#define RANKD 396
#define WEMB  400
#define TEMB  20
#define TAGS  25
#define BATCH 16
#define LSEQ  128
#define MROWS 126        // L-2
#define NM    2016       // 16*126
#define NMP   2048
#define ABC   15625
#define ABCP  15744      // 123*128
#define SCALE 0.050251890762960605f   // 1/sqrt(396)

typedef __attribute__((ext_vector_type(8))) short short8;
typedef __attribute__((ext_vector_type(4))) float f32x4;

// workspace layout (bytes)
#define OFF_T01  0                         // 2048*416*2      = 1,703,936
#define OFF_T02  1703936                   // 15744*416*2     = 13,099,008
#define OFF_WORD 14802944                  // 16*128*416*2    = 1,703,936
#define OFF_WT   16506880                  // 3*416*416*2     = 1,038,336
#define OFF_G    17545216                  // 3*25*416*4      = 124,800

#define GLOAD_LDS16(gp, lp) \
  __builtin_amdgcn_global_load_lds((const __attribute__((address_space(1))) uint32_t*)(gp), \
                                   (__attribute__((address_space(3))) uint32_t*)(lp), 16, 0, 0)

__device__ __forceinline__ uint16_t f2bf(float f) {
    union { float f; uint32_t u; } v; v.f = f;
    uint32_t u = v.u;
    return (uint16_t)((u + 0x7FFFu + ((u >> 16) & 1u)) >> 16);  // RNE
}

// ---- prep: word->bf16 pad | W->Wt bf16 pad | g4/g5/g6 fp32 (fused by block range)
#define J1_BLK 3328   // 16*128*416/256
#define J2_BLK 2028   // 3*416*416/256
#define J3_BLK 122    // ceil(3*25*416/256)
__global__ void k_prep(const float* __restrict__ word,
                       const float* __restrict__ W1, const float* __restrict__ W2,
                       const float* __restrict__ W3, const float* __restrict__ tag,
                       const float* __restrict__ T1, const float* __restrict__ T2,
                       const float* __restrict__ T3,
                       uint16_t* __restrict__ wordb, uint16_t* __restrict__ wt,
                       float* __restrict__ g) {
    int bx = blockIdx.x;
    if (bx < J1_BLK) {
        int idx = bx * 256 + threadIdx.x;
        int e = idx % KP, row = idx / KP;
        wordb[idx] = f2bf((e < WEMB) ? word[row * WEMB + e] : 0.f);
    } else if (bx < J1_BLK + J2_BLK) {
        int idx = (bx - J1_BLK) * 256 + threadIdx.x;
        int j = idx / (KP * KP);
        int rem = idx % (KP * KP);
        int k = rem / KP, e = rem % KP;
        const float* W = (j == 0) ? W1 : (j == 1) ? W2 : W3;
        wt[idx] = f2bf((k < RANKD && e < WEMB) ? W[e * RANKD + k] : 0.f);
    } else {
        int idx = (bx - J1_BLK - J2_BLK) * 256 + threadIdx.x;
        if (idx >= 3 * TAGS * KP) return;
        int j = idx / (TAGS * KP);
        int rem = idx % (TAGS * KP);
        int a = rem / KP, k = rem % KP;
        const float* T = (j == 0) ? T1 : (j == 1) ? T2 : T3;
        float s = 0.f;
        if (k < RANKD) {
            for (int e = 0; e < TEMB; ++e) s += tag[a * TEMB + e] * T[e * RANKD + k];
        }
        g[idx] = s;
    }
}

// ---- mid: t01 build (MFMA) blocks [0,896) | t02 build blocks [896,4094)
#define T01_BLK 896    // 128 nm-tiles * 7 k-groups
#define T02_BLK 3198   // 15744*52/256
__global__ __launch_bounds__(256) void k_mid(const uint16_t* __restrict__ word,
                                             const uint16_t* __restrict__ wt,
                                             const float* __restrict__ g,
                                             uint16_t* __restrict__ t01,
                                             uint16_t* __restrict__ t02) {
    int bx = blockIdx.x;
    if (bx < T01_BLK) {
        int wid = threadIdx.x >> 6, lane = threadIdx.x & 63;
        int nmtile = bx & 127;
        int ktile = (bx >> 7) * 4 + wid;
        if (ktile >= KP / 16) return;
        int col_l = lane & 15, kblk = lane >> 4;
        int colk = ktile * 16 + col_l;
        f32x4 acc1 = {0.f, 0.f, 0.f, 0.f}, acc2 = acc1, acc3 = acc1;
        if (nmtile < NM / 16) {
            int nm_a = nmtile * 16 + col_l;
            int n = nm_a / MROWS, m = nm_a % MROWS;
            const uint16_t* arow = word + (size_t)(n * LSEQ + m) * KP;
            const uint16_t* b1 = wt + (size_t)colk * KP;
            const uint16_t* b2 = wt + (size_t)KP * KP + (size_t)colk * KP;
            const uint16_t* b3 = wt + (size_t)2 * KP * KP + (size_t)colk * KP;
            for (int e0 = 0; e0 < KP; e0 += 32) {
                int eo = e0 + kblk * 8;
                short8 a0 = *(const short8*)(arow + eo);
                short8 a1 = *(const short8*)(arow + KP + eo);
                short8 a2 = *(const short8*)(arow + 2 * KP + eo);
                short8 v1 = *(const short8*)(b1 + eo);
                short8 v2 = *(const short8*)(b2 + eo);
                short8 v3 = *(const short8*)(b3 + eo);
                acc1 = __builtin_amdgcn_mfma_f32_16x16x32_bf16(a0, v1, acc1, 0, 0, 0);
                acc2 = __builtin_amdgcn_mfma_f32_16x16x32_bf16(a1, v2, acc2, 0, 0, 0);
                acc3 = __builtin_amdgcn_mfma_f32_16x16x32_bf16(a2, v3, acc3, 0, 0, 0);
            }
        }
        for (int r = 0; r < 4; ++r) {
            int row = nmtile * 16 + kblk * 4 + r;
            float v = acc1[r] * acc2[r] * acc3[r] * SCALE;
            t01[(size_t)row * KP + colk] = f2bf(v);
        }
    } else {
        int idx = (bx - T01_BLK) * 256 + threadIdx.x;
        int abc = idx / (KP / 8), kc = idx % (KP / 8);
        int k0 = kc * 8;
        short8 o;
        if (abc < ABC) {
            int a = abc / 625, rem = abc % 625, b = rem / 25, c = rem % 25;
            const float4* ga = (const float4*)(g + (size_t)a * KP + k0);
            const float4* gb = (const float4*)(g + (size_t)TAGS * KP + (size_t)b * KP + k0);
            const float4* gc = (const float4*)(g + (size_t)2 * TAGS * KP + (size_t)c * KP + k0);
            float4 a0 = ga[0], a1 = ga[1];
            float4 b0 = gb[0], b1 = gb[1];
            float4 c0 = gc[0], c1 = gc[1];
            o[0] = (short)f2bf(a0.x * b0.x * c0.x);
            o[1] = (short)f2bf(a0.y * b0.y * c0.y);
            o[2] = (short)f2bf(a0.z * b0.z * c0.z);
            o[3] = (short)f2bf(a0.w * b0.w * c0.w);
            o[4] = (short)f2bf(a1.x * b1.x * c1.x);
            o[5] = (short)f2bf(a1.y * b1.y * c1.y);
            o[6] = (short)f2bf(a1.z * b1.z * c1.z);
            o[7] = (short)f2bf(a1.w * b1.w * c1.w);
        } else {
            for (int t = 0; t < 8; ++t) o[t] = 0;
        }
        *(short8*)(t02 + (size_t)abc * KP + k0) = o;
    }
}

// ---- final: score[2016][15625] = t01 @ t02^T  (m97 structure: 128x128 tile,
//      BK=32, double-buffered LDS via global_load_lds width=16, 2 barriers/K-step)
__global__ __launch_bounds__(256) void k_final(const uint16_t* __restrict__ t01,
                                               const uint16_t* __restrict__ t02,
                                               float* __restrict__ out) {
    __shared__ uint16_t lds[2][2][128 * 32];   // [buf][A/B][row*32+k] = 32 KB
    int tid = threadIdx.x;
    int wid = tid >> 6, lane = tid & 63;
    int col_l = lane & 15, kblk = lane >> 4;
    int brow = blockIdx.x * 128, bcol = blockIdx.y * 128;
    int wrow = (wid >> 1) * 64, wcol = (wid & 1) * 64;

    // staging geometry: chunk c covers LDS bytes [(wid+4c)*1024, +1024)
    int off0 = wid * 1024;            // wave-uniform LDS byte base, chunk 0
    int off1 = (wid + 4) * 1024;      // chunk 1
    int by0 = off0 + lane * 16, by1 = off1 + lane * 16;
    int r0 = by0 >> 6, ks0 = (by0 >> 4) & 3;   // row (64B/row), 16B slot
    int r1 = by1 >> 6, ks1 = (by1 >> 4) & 3;

    const uint16_t* ga0 = t01 + (size_t)(brow + r0) * KP + ks0 * 8;
    const uint16_t* ga1 = t01 + (size_t)(brow + r1) * KP + ks1 * 8;
    const uint16_t* gb0 = t02 + (size_t)(bcol + r0) * KP + ks0 * 8;
    const uint16_t* gb1 = t02 + (size_t)(bcol + r1) * KP + ks1 * 8;

    f32x4 acc[4][4];
#pragma unroll
    for (int i = 0; i < 4; ++i)
#pragma unroll
        for (int j = 0; j < 4; ++j)
            acc[i][j] = (f32x4){0.f, 0.f, 0.f, 0.f};

    auto stage = [&](int buf, int kk) {
        GLOAD_LDS16(ga0 + kk, &lds[buf][0][off0 >> 1]);
        GLOAD_LDS16(ga1 + kk, &lds[buf][0][off1 >> 1]);
        GLOAD_LDS16(gb0 + kk, &lds[buf][1][off0 >> 1]);
        GLOAD_LDS16(gb1 + kk, &lds[buf][1][off1 >> 1]);
    };

    const int NT = KP / 32;   // 13
    stage(0, 0);
    for (int kt = 0; kt < NT; ++kt) {
        int cur = kt & 1;
        if (kt + 1 < NT) stage(cur ^ 1, (kt + 1) * 32);
        __syncthreads();                       // loads for `cur` complete here
        const uint16_t* la = &lds[cur][0][0];
        const uint16_t* lb = &lds[cur][1][0];
        short8 a[4], b[4];
#pragma unroll
        for (int i = 0; i < 4; ++i)
            a[i] = *(const short8*)(la + (wrow + i * 16 + col_l) * 32 + kblk * 8);
#pragma unroll
        for (int j = 0; j < 4; ++j)
            b[j] = *(const short8*)(lb + (wcol + j * 16 + col_l) * 32 + kblk * 8);
#pragma unroll
        for (int i = 0; i < 4; ++i)
#pragma unroll
            for (int j = 0; j < 4; ++j)
                acc[i][j] = __builtin_amdgcn_mfma_f32_16x16x32_bf16(a[i], b[j], acc[i][j], 0, 0, 0);
        __syncthreads();                       // protect `cur` until all waves done
    }

#pragma unroll
    for (int i = 0; i < 4; ++i) {
        int row_b = brow + wrow + i * 16 + kblk * 4;
#pragma unroll
        for (int j = 0; j < 4; ++j) {
            int col = bcol + wcol + j * 16 + col_l;
            if (col >= ABC) continue;
#pragma unroll
            for (int r = 0; r < 4; ++r) {
                int row = row_b + r;
                if (row < NM) out[(size_t)row * ABC + col] = acc[i][j][r];
            }
        }
    }
}

extern "C" void kernel_launch(void* const* d_in, const int* in_sizes, int n_in,
                              void* d_out, int out_size, void* d_ws, size_t ws_size,
                              hipStream_t stream) {
    const float* word = (const float*)d_in[0];
    const float* tag  = (const float*)d_in[1];
    const float* W1   = (const float*)d_in[2];
    const float* W2   = (const float*)d_in[3];
    const float* W3   = (const float*)d_in[4];
    const float* T1   = (const float*)d_in[5];
    const float* T2   = (const float*)d_in[6];
    const float* T3   = (const float*)d_in[7];
    float* out = (float*)d_out;
    char* ws = (char*)d_ws;

    uint16_t* t01   = (uint16_t*)(ws + OFF_T01);
    uint16_t* t02   = (uint16_t*)(ws + OFF_T02);
    uint16_t* wordb = (uint16_t*)(ws + OFF_WORD);
    uint16_t* wt    = (uint16_t*)(ws + OFF_WT);
    float*    g     = (float*)(ws + OFF_G);

    k_prep<<<J1_BLK + J2_BLK + J3_BLK, 256, 0, stream>>>(word, W1, W2, W3, tag,
                                                         T1, T2, T3, wordb, wt, g);
    k_mid<<<T01_BLK + T02_BLK, 256, 0, stream>>>(wordb, wt, g, t01, t02);
    k_final<<<dim3(NMP / 128, ABCP / 128), 256, 0, stream>>>(t01, t02, out);
}